// Round 9
// baseline (218.829 us; speedup 1.0000x reference)
//
#include <hip/hip_runtime.h>
#include <math.h>
#include <float.h>

// Problem constants
#define NTOK 65536
#define NCB  4
#define MCODE 512
#define DIM  64

#define QST_SIZE (NTOK * NCB * DIM)        // 16777216
#define IDX_OFF  (QST_SIZE + 3)            // 16777219

// Tiles: 4 waves/block, each wave owns 64 tokens = TWO 32-wide MFMA column
// tiles sharing every A-load / d0 / barrier (halves barrier count vs R5,
// doubles per-interval MFMA density, 2 independent dep chains for ILP).
#define TOK_TILE  256

// ws layout (bytes):
//   ehf f16[4*16*4*512] @ 0        (262144)  hi half of 512*e, MFMA-fragment order
//   elf f16[4*16*4*512] @ 262144   (262144)  lo half, fragment order
//   d0p f32[2048]       @ 524288   (8192)    -256 * sum(e^2)  (acc C-init)
//   counts int[2048]    @ 532480   (8192)
//   lossSum f32         @ 540672
#define WS_EH 0
#define WS_EL 262144
#define WS_D0 524288
#define WS_CNT 532480
#define WS_LOSS 540672

typedef _Float16 half8 __attribute__((ext_vector_type(8)));
typedef float floatx16 __attribute__((ext_vector_type(16)));

// ---- prep: wave-per-row fragment-order f16 hi/lo split of 512*e ----
// (R8 version — 2048 rows, 1 wave each, 512 blocks x 256 thr)
__global__ __launch_bounds__(256) void prep_kernel(const float* __restrict__ emb,
                                                   _Float16* __restrict__ ehf,
                                                   _Float16* __restrict__ elf,
                                                   float* __restrict__ d0p,
                                                   int* __restrict__ counts,
                                                   float* __restrict__ lossSum) {
    const int tid  = threadIdx.x;
    const int lane = tid & 63;
    const int row  = blockIdx.x * 4 + (tid >> 6);   // 0..2047
    const int c    = row >> 9;
    const int n    = row & 511;
    const int nt   = n >> 5;
    const int r5   = n & 31;

    const float e = emb[(size_t)row * DIM + lane];

    // wave-reduce |e|^2
    float s = e * e;
#pragma unroll
    for (int off = 32; off > 0; off >>= 1) s += __shfl_xor(s, off);

    // hi/lo split of 512*e
    const float f = e * 512.0f;
    const _Float16 hv = (_Float16)f;
    const _Float16 lv = (_Float16)(f - (float)hv);

    const int ch = lane >> 4;
    const int h  = (lane >> 3) & 1;
    const int t  = lane & 7;
    const size_t off = ((size_t)((c * 16 + nt) * 4 + ch)) * 512 + (h * 32 + r5) * 8 + t;
    ehf[off] = hv;
    elf[off] = lv;

    if (lane == 0) {
        d0p[row] = -256.0f * s;
        counts[row] = 0;
        if (row == 0) *lossSum = 0.f;
    }
}

// ---- main: 32x32x16 MFMA + per-lane argmin; A staged through dbuf LDS ----
// A = codes (block-shared LDS stream), B = tokens (2 persistent sets/wave).
// Per nt: prefetch chunk nt+1 global->regs (top), compute nt from LDS with
// TWO interleaved independent 12-MFMA chains, ds_write, one barrier.
__global__ __launch_bounds__(256) void vq_main(const float* __restrict__ x,
                                               const float* __restrict__ emb,
                                               const float* __restrict__ mask,
                                               const _Float16* __restrict__ ehf,
                                               const _Float16* __restrict__ elf,
                                               const float* __restrict__ d0p,
                                               int* __restrict__ counts,
                                               float* __restrict__ lossSum,
                                               float* __restrict__ outQ,
                                               float* __restrict__ outIdx) {
    __shared__ __align__(16) _Float16 As[2][4096];   // [buf][eh 2048 | el 2048] = 16 KB
    __shared__ __align__(16) float d0s[MCODE];       // 2 KB
    __shared__ int   Is[TOK_TILE];
    __shared__ float wls[4];

    const int tid  = threadIdx.x;
    const int c    = blockIdx.y;
    const int n0tk = blockIdx.x * TOK_TILE;
    const int lane = tid & 63;
    const int w    = tid >> 6;            // wave id 0..3
    const int l31  = lane & 31;           // token within tile / acc column
    const int hi   = lane >> 5;           // k-half for A/B, row-half for C
    const int hi4  = hi * 4;

    const _Float16* gEh = ehf + (size_t)c * (16 * 4 * 512);
    const _Float16* gEl = elf + (size_t)c * (16 * 4 * 512);

    // ---- stage chunk 0 + d0 into LDS (loads first, overlap with B-build) ----
    float4 sh = *(const float4*)(gEh + tid * 8);
    float4 sl = *(const float4*)(gEl + tid * 8);
    float4 dstage;
    if (tid < 128) dstage = *(const float4*)(d0p + c * MCODE + tid * 4);

    // ---- persistent B fragments (x hi/lo), TWO token sets per wave ----
    // set s tokens: n0tk + w*64 + s*32 + l31 ; k = ch*16 + hi*8 + t
    half8 B0h[4], B0l[4], B1h[4], B1l[4];
#pragma unroll
    for (int s = 0; s < 2; ++s) {
        const float* xr = x + (size_t)(n0tk + w * 64 + s * 32 + l31) * (NCB * DIM) + c * DIM + hi * 8;
#pragma unroll
        for (int ch = 0; ch < 4; ++ch) {
            float fv[8];
            *(float4*)(fv)     = *(const float4*)(xr + ch * 16);
            *(float4*)(fv + 4) = *(const float4*)(xr + ch * 16 + 4);
            half8 h8, l8;
#pragma unroll
            for (int t = 0; t < 8; ++t) {
                float f = fv[t];
                _Float16 hh = (_Float16)f;
                h8[t] = hh;
                l8[t] = (_Float16)(f - (float)hh);
            }
            if (s == 0) { B0h[ch] = h8; B0l[ch] = l8; }
            else        { B1h[ch] = h8; B1l[ch] = l8; }
        }
    }

    *(float4*)((char*)&As[0][0]    + tid * 16) = sh;
    *(float4*)((char*)&As[0][2048] + tid * 16) = sl;
    if (tid < 128) *(float4*)(&d0s[tid * 4]) = dstage;
    __syncthreads();

    float maxv0 = -FLT_MAX, maxv1 = -FLT_MAX;
    int   maxn0 = 0,        maxn1 = 0;

    // ---- sweep 16 n-tiles of 32 codes, dbuf LDS + 1-ahead prefetch ----
    for (int nt = 0; nt < 16; ++nt) {
        const int p = nt & 1;

        // prefetch next chunk to regs (latency hides under 24 MFMAs below)
        float4 nh, nl;
        if (nt < 15) {
            nh = *(const float4*)(gEh + (nt + 1) * 2048 + tid * 8);
            nl = *(const float4*)(gEl + (nt + 1) * 2048 + tid * 8);
        }

        // A fragment reads from LDS (shared by both token sets)
        const _Float16* ah = &As[p][0] + lane * 8;
        const _Float16* al = &As[p][2048] + lane * 8;
        half8 Ah0 = *(const half8*)(ah);
        half8 Ah1 = *(const half8*)(ah + 512);
        half8 Ah2 = *(const half8*)(ah + 1024);
        half8 Ah3 = *(const half8*)(ah + 1536);
        half8 Al0 = *(const half8*)(al);
        half8 Al1 = *(const half8*)(al + 512);
        half8 Al2 = *(const half8*)(al + 1024);
        half8 Al3 = *(const half8*)(al + 1536);

        // acc C-init = -256*|e|^2 per code row (shared by both sets)
        const float* dpt = &d0s[nt * 32 + hi4];
        float4 d40 = *(const float4*)(dpt);
        float4 d41 = *(const float4*)(dpt + 8);
        float4 d42 = *(const float4*)(dpt + 16);
        float4 d43 = *(const float4*)(dpt + 24);
        floatx16 acc0, acc1;
        acc0[0]  = d40.x; acc0[1]  = d40.y; acc0[2]  = d40.z; acc0[3]  = d40.w;
        acc0[4]  = d41.x; acc0[5]  = d41.y; acc0[6]  = d41.z; acc0[7]  = d41.w;
        acc0[8]  = d42.x; acc0[9]  = d42.y; acc0[10] = d42.z; acc0[11] = d42.w;
        acc0[12] = d43.x; acc0[13] = d43.y; acc0[14] = d43.z; acc0[15] = d43.w;
        acc1 = acc0;

        // 24 MFMA: two independent interleaved 12-chains (per-set order
        // identical to R5 -> bitwise-identical results per token)
        acc0 = __builtin_amdgcn_mfma_f32_32x32x16_f16(Ah0, B0h[0], acc0, 0, 0, 0);
        acc1 = __builtin_amdgcn_mfma_f32_32x32x16_f16(Ah0, B1h[0], acc1, 0, 0, 0);
        acc0 = __builtin_amdgcn_mfma_f32_32x32x16_f16(Al0, B0h[0], acc0, 0, 0, 0);
        acc1 = __builtin_amdgcn_mfma_f32_32x32x16_f16(Al0, B1h[0], acc1, 0, 0, 0);
        acc0 = __builtin_amdgcn_mfma_f32_32x32x16_f16(Ah0, B0l[0], acc0, 0, 0, 0);
        acc1 = __builtin_amdgcn_mfma_f32_32x32x16_f16(Ah0, B1l[0], acc1, 0, 0, 0);
        acc0 = __builtin_amdgcn_mfma_f32_32x32x16_f16(Ah1, B0h[1], acc0, 0, 0, 0);
        acc1 = __builtin_amdgcn_mfma_f32_32x32x16_f16(Ah1, B1h[1], acc1, 0, 0, 0);
        acc0 = __builtin_amdgcn_mfma_f32_32x32x16_f16(Al1, B0h[1], acc0, 0, 0, 0);
        acc1 = __builtin_amdgcn_mfma_f32_32x32x16_f16(Al1, B1h[1], acc1, 0, 0, 0);
        acc0 = __builtin_amdgcn_mfma_f32_32x32x16_f16(Ah1, B0l[1], acc0, 0, 0, 0);
        acc1 = __builtin_amdgcn_mfma_f32_32x32x16_f16(Ah1, B1l[1], acc1, 0, 0, 0);
        acc0 = __builtin_amdgcn_mfma_f32_32x32x16_f16(Ah2, B0h[2], acc0, 0, 0, 0);
        acc1 = __builtin_amdgcn_mfma_f32_32x32x16_f16(Ah2, B1h[2], acc1, 0, 0, 0);
        acc0 = __builtin_amdgcn_mfma_f32_32x32x16_f16(Al2, B0h[2], acc0, 0, 0, 0);
        acc1 = __builtin_amdgcn_mfma_f32_32x32x16_f16(Al2, B1h[2], acc1, 0, 0, 0);
        acc0 = __builtin_amdgcn_mfma_f32_32x32x16_f16(Ah2, B0l[2], acc0, 0, 0, 0);
        acc1 = __builtin_amdgcn_mfma_f32_32x32x16_f16(Ah2, B1l[2], acc1, 0, 0, 0);
        acc0 = __builtin_amdgcn_mfma_f32_32x32x16_f16(Ah3, B0h[3], acc0, 0, 0, 0);
        acc1 = __builtin_amdgcn_mfma_f32_32x32x16_f16(Ah3, B1h[3], acc1, 0, 0, 0);
        acc0 = __builtin_amdgcn_mfma_f32_32x32x16_f16(Al3, B0h[3], acc0, 0, 0, 0);
        acc1 = __builtin_amdgcn_mfma_f32_32x32x16_f16(Al3, B1h[3], acc1, 0, 0, 0);
        acc0 = __builtin_amdgcn_mfma_f32_32x32x16_f16(Ah3, B0l[3], acc0, 0, 0, 0);
        acc1 = __builtin_amdgcn_mfma_f32_32x32x16_f16(Ah3, B1l[3], acc1, 0, 0, 0);

        // per-lane argmin: two independent serial chains (interleaved)
        // n(r) = nt*32 + hi4 + (r&3) + 8*(r>>2), increasing in (nt, r):
        // strict '>' keeps first (lowest index) max => first-min of distance
        const int nbase = nt * 32 + hi4;
#pragma unroll
        for (int r = 0; r < 16; ++r) {
            const int n = nbase + ((r & 3) + 8 * (r >> 2));
            float m0 = acc0[r];
            float m1 = acc1[r];
            if (m0 > maxv0) { maxv0 = m0; maxn0 = n; }
            if (m1 > maxv1) { maxv1 = m1; maxn1 = n; }
        }

        // write prefetched chunk into the other buffer (vmcnt drain lands
        // here, after compute), then one barrier ends the iteration
        if (nt < 15) {
            *(float4*)((char*)&As[p ^ 1][0]    + tid * 16) = nh;
            *(float4*)((char*)&As[p ^ 1][2048] + tid * 16) = nl;
        }
        __syncthreads();
    }

    // ---- merge the two row-halves (lane <-> lane+32), per set ----
    {
        float ov = __shfl_xor(maxv0, 32);
        int   on = __shfl_xor(maxn0, 32);
        if (ov > maxv0 || (ov == maxv0 && on < maxn0)) { maxv0 = ov; maxn0 = on; }
        ov = __shfl_xor(maxv1, 32);
        on = __shfl_xor(maxn1, 32);
        if (ov > maxv1 || (ov == maxv1 && on < maxn1)) { maxv1 = ov; maxn1 = on; }
    }

    if (hi == 0) {
        Is[w * 64 + l31]      = maxn0;
        Is[w * 64 + 32 + l31] = maxn1;
        atomicAdd(&counts[c * MCODE + maxn0], 1);
        atomicAdd(&counts[c * MCODE + maxn1], 1);
        outIdx[(size_t)(n0tk + w * 64 + l31) * NCB + c]      = (float)maxn0;
        outIdx[(size_t)(n0tk + w * 64 + 32 + l31) * NCB + c] = (float)maxn1;
    }
    __syncthreads();

    // ---- quantized_st + loss (original fp32 emb + fp32 x for exactness) ----
    float lloss = 0.f;
#pragma unroll
    for (int i = 0; i < 16; ++i) {
        int q = tid + i * 256;
        int tok = q >> 4, d4 = q & 15;
        int idx = Is[tok];
        float mv = mask[(size_t)(n0tk + tok) * NCB + c];
        float4 e4 = *(const float4*)(emb + ((size_t)c * MCODE + idx) * DIM + d4 * 4);
        float4 x4 = *(const float4*)(x + (size_t)(n0tk + tok) * (NCB * DIM) + c * DIM + d4 * 4);
        float qx = e4.x * mv, qy = e4.y * mv, qz = e4.z * mv, qw = e4.w * mv;
        float4 o;
        o.x = x4.x + (qx - x4.x);
        o.y = x4.y + (qy - x4.y);
        o.z = x4.z + (qz - x4.z);
        o.w = x4.w + (qw - x4.w);
        *(float4*)(outQ + (size_t)(n0tk + tok) * (NCB * DIM) + c * DIM + d4 * 4) = o;
        float dx = x4.x - qx, dy = x4.y - qy, dz = x4.z - qz, dw = x4.w - qw;
        lloss += dx * dx + dy * dy + dz * dz + dw * dw;
    }
#pragma unroll
    for (int off = 32; off > 0; off >>= 1) lloss += __shfl_xor(lloss, off);
    if ((tid & 63) == 0) wls[tid >> 6] = lloss;
    __syncthreads();
    if (tid == 0) {
        float s = wls[0] + wls[1] + wls[2] + wls[3];
        atomicAdd(lossSum, s);
    }
}

__global__ __launch_bounds__(256) void finalize_kernel(const int* __restrict__ counts,
                                                       const float* __restrict__ lossSum,
                                                       float* __restrict__ out) {
    __shared__ float wls[4];
    int tid = threadIdx.x;
    float s = 0.f;
#pragma unroll
    for (int i = 0; i < 8; ++i) {
        int j = tid + i * 256;
        float p = (float)counts[j] * (1.0f / 65536.0f);
        s += p * logf(p + 1e-10f);
    }
#pragma unroll
    for (int off = 32; off > 0; off >>= 1) s += __shfl_xor(s, off);
    if ((tid & 63) == 0) wls[tid >> 6] = s;
    __syncthreads();
    if (tid == 0) {
        float tot = wls[0] + wls[1] + wls[2] + wls[3];
        float L = *lossSum * (1.0f / (float)QST_SIZE);
        out[QST_SIZE + 0] = 0.25f * L;   // commitment_loss
        out[QST_SIZE + 1] = L;           // codebook_loss
        out[QST_SIZE + 2] = expf(-tot);  // perplexity
    }
}

extern "C" void kernel_launch(void* const* d_in, const int* in_sizes, int n_in,
                              void* d_out, int out_size, void* d_ws, size_t ws_size,
                              hipStream_t stream) {
    const float* x    = (const float*)d_in[0];
    const float* emb  = (const float*)d_in[1];
    const float* mask = (const float*)d_in[2];
    float* out = (float*)d_out;

    _Float16* ehf  = (_Float16*)((char*)d_ws + WS_EH);
    _Float16* elf  = (_Float16*)((char*)d_ws + WS_EL);
    float* d0p     = (float*)((char*)d_ws + WS_D0);
    int*   counts  = (int*)((char*)d_ws + WS_CNT);
    float* lossSum = (float*)((char*)d_ws + WS_LOSS);

    prep_kernel<<<dim3(512), dim3(256), 0, stream>>>(emb, ehf, elf, d0p, counts, lossSum);
    vq_main<<<dim3(NTOK / TOK_TILE, NCB), dim3(256), 0, stream>>>(
        x, emb, mask, ehf, elf, d0p, counts, lossSum, out, out + IDX_OFF);
    finalize_kernel<<<dim3(1), dim3(256), 0, stream>>>(counts, lossSum, out);
}

// Round 10
// 197.930 us; speedup vs baseline: 1.1056x; 1.1056x over previous
//
#include <hip/hip_runtime.h>
#include <math.h>
#include <float.h>

// Problem constants
#define NTOK 65536
#define NCB  4
#define MCODE 512
#define DIM  64

#define QST_SIZE (NTOK * NCB * DIM)        // 16777216
#define IDX_OFF  (QST_SIZE + 3)            // 16777219

// Tiles: 4 waves/block, each wave owns 32 tokens (one 32-wide MFMA column tile)
#define TOK_TILE  128

// ws layout (bytes):
//   ehf f16[4*16*4*512] @ 0        (262144)  hi half of 512*e, MFMA-fragment order
//   elf f16[4*16*4*512] @ 262144   (262144)  lo half, fragment order
//   d0p f32[2048]       @ 524288   (8192)    -256 * sum(e^2)  (acc C-init)
//   counts int[2048]    @ 532480   (8192)
//   lossSum f32         @ 540672
#define WS_EH 0
#define WS_EL 262144
#define WS_D0 524288
#define WS_CNT 532480
#define WS_LOSS 540672

typedef _Float16 half8 __attribute__((ext_vector_type(8)));
typedef float floatx16 __attribute__((ext_vector_type(16)));

// ---- prep: wave-per-row fragment-order f16 hi/lo split of 512*e ----
// (R8 version — 2048 rows, 1 wave each, 512 blocks x 256 thr)
__global__ __launch_bounds__(256) void prep_kernel(const float* __restrict__ emb,
                                                   _Float16* __restrict__ ehf,
                                                   _Float16* __restrict__ elf,
                                                   float* __restrict__ d0p,
                                                   int* __restrict__ counts,
                                                   float* __restrict__ lossSum) {
    const int tid  = threadIdx.x;
    const int lane = tid & 63;
    const int row  = blockIdx.x * 4 + (tid >> 6);   // 0..2047
    const int c    = row >> 9;
    const int n    = row & 511;
    const int nt   = n >> 5;
    const int r5   = n & 31;

    const float e = emb[(size_t)row * DIM + lane];

    // wave-reduce |e|^2
    float s = e * e;
#pragma unroll
    for (int off = 32; off > 0; off >>= 1) s += __shfl_xor(s, off);

    // hi/lo split of 512*e
    const float f = e * 512.0f;
    const _Float16 hv = (_Float16)f;
    const _Float16 lv = (_Float16)(f - (float)hv);

    const int ch = lane >> 4;
    const int h  = (lane >> 3) & 1;
    const int t  = lane & 7;
    const size_t off = ((size_t)((c * 16 + nt) * 4 + ch)) * 512 + (h * 32 + r5) * 8 + t;
    ehf[off] = hv;
    elf[off] = lv;

    if (lane == 0) {
        d0p[row] = -256.0f * s;
        counts[row] = 0;
        if (row == 0) *lossSum = 0.f;
    }
}

// ---- main: 32x32x16 MFMA + per-lane argmin; A staged through dbuf LDS ----
// (verbatim best-measured kernel: 112.6-117.9 us, occ ~35%, VGPR 64)
// A = codes (block-shared LDS stream), B = tokens (persistent, 32 VGPR).
// Per nt: prefetch chunk nt+1 global->regs (top), compute nt from LDS,
// ds_write regs->LDS[buf^1] (bottom), one barrier. 4x A-traffic reduction.
__global__ __launch_bounds__(256) void vq_main(const float* __restrict__ x,
                                               const float* __restrict__ emb,
                                               const float* __restrict__ mask,
                                               const _Float16* __restrict__ ehf,
                                               const _Float16* __restrict__ elf,
                                               const float* __restrict__ d0p,
                                               int* __restrict__ counts,
                                               float* __restrict__ lossSum,
                                               float* __restrict__ outQ,
                                               float* __restrict__ outIdx) {
    __shared__ __align__(16) _Float16 As[2][4096];   // [buf][eh 2048 | el 2048] = 16 KB
    __shared__ __align__(16) float d0s[MCODE];       // 2 KB
    __shared__ int   Is[TOK_TILE];
    __shared__ float wls[4];

    const int tid  = threadIdx.x;
    const int c    = blockIdx.y;
    const int n0tk = blockIdx.x * TOK_TILE;
    const int lane = tid & 63;
    const int w    = tid >> 6;            // wave id 0..3
    const int l31  = lane & 31;           // token within wave tile / acc column
    const int hi   = lane >> 5;           // k-half for A/B, row-half for C
    const int hi4  = hi * 4;

    const _Float16* gEh = ehf + (size_t)c * (16 * 4 * 512);
    const _Float16* gEl = elf + (size_t)c * (16 * 4 * 512);

    // ---- stage chunk 0 + d0 into LDS (loads first, for overlap with B-build) ----
    float4 sh = *(const float4*)(gEh + tid * 8);
    float4 sl = *(const float4*)(gEl + tid * 8);
    float4 dstage;
    if (tid < 128) dstage = *(const float4*)(d0p + c * MCODE + tid * 4);

    // ---- persistent B fragments (x hi/lo) for this lane's token ----
    // B col = lane&31 = token; k = ch*16 + hi*8 + t
    half8 Bh[4], Bl[4];
    {
        const float* xr = x + (size_t)(n0tk + w * 32 + l31) * (NCB * DIM) + c * DIM + hi * 8;
#pragma unroll
        for (int ch = 0; ch < 4; ++ch) {
            float fv[8];
            *(float4*)(fv)     = *(const float4*)(xr + ch * 16);
            *(float4*)(fv + 4) = *(const float4*)(xr + ch * 16 + 4);
            half8 h8, l8;
#pragma unroll
            for (int t = 0; t < 8; ++t) {
                float f = fv[t];
                _Float16 hh = (_Float16)f;
                h8[t] = hh;
                l8[t] = (_Float16)(f - (float)hh);
            }
            Bh[ch] = h8;
            Bl[ch] = l8;
        }
    }

    *(float4*)((char*)&As[0][0]    + tid * 16) = sh;
    *(float4*)((char*)&As[0][2048] + tid * 16) = sl;
    if (tid < 128) *(float4*)(&d0s[tid * 4]) = dstage;
    __syncthreads();

    float maxv = -FLT_MAX;
    int   maxn = 0;

    // ---- sweep 16 n-tiles of 32 codes, dbuf LDS + 1-ahead prefetch ----
    for (int nt = 0; nt < 16; ++nt) {
        const int p = nt & 1;

        // prefetch next chunk to regs (latency hides under MFMA+argmin below)
        float4 nh, nl;
        if (nt < 15) {
            nh = *(const float4*)(gEh + (nt + 1) * 2048 + tid * 8);
            nl = *(const float4*)(gEl + (nt + 1) * 2048 + tid * 8);
        }

        // A fragment reads from LDS (stride-1 b128, standard pattern)
        const _Float16* ah = &As[p][0] + lane * 8;
        const _Float16* al = &As[p][2048] + lane * 8;
        half8 Ah0 = *(const half8*)(ah);
        half8 Ah1 = *(const half8*)(ah + 512);
        half8 Ah2 = *(const half8*)(ah + 1024);
        half8 Ah3 = *(const half8*)(ah + 1536);
        half8 Al0 = *(const half8*)(al);
        half8 Al1 = *(const half8*)(al + 512);
        half8 Al2 = *(const half8*)(al + 1024);
        half8 Al3 = *(const half8*)(al + 1536);

        // acc C-init = -256*|e|^2 per code row (LDS broadcast reads)
        const float* dpt = &d0s[nt * 32 + hi4];
        float4 d40 = *(const float4*)(dpt);
        float4 d41 = *(const float4*)(dpt + 8);
        float4 d42 = *(const float4*)(dpt + 16);
        float4 d43 = *(const float4*)(dpt + 24);
        floatx16 acc;
        acc[0]  = d40.x; acc[1]  = d40.y; acc[2]  = d40.z; acc[3]  = d40.w;
        acc[4]  = d41.x; acc[5]  = d41.y; acc[6]  = d41.z; acc[7]  = d41.w;
        acc[8]  = d42.x; acc[9]  = d42.y; acc[10] = d42.z; acc[11] = d42.w;
        acc[12] = d43.x; acc[13] = d43.y; acc[14] = d43.z; acc[15] = d43.w;

        // 12-MFMA chain: (Ah+Al)(Bh+Bl) ≈ AhBh + AlBh + AhBl per k-chunk
        acc = __builtin_amdgcn_mfma_f32_32x32x16_f16(Ah0, Bh[0], acc, 0, 0, 0);
        acc = __builtin_amdgcn_mfma_f32_32x32x16_f16(Al0, Bh[0], acc, 0, 0, 0);
        acc = __builtin_amdgcn_mfma_f32_32x32x16_f16(Ah0, Bl[0], acc, 0, 0, 0);
        acc = __builtin_amdgcn_mfma_f32_32x32x16_f16(Ah1, Bh[1], acc, 0, 0, 0);
        acc = __builtin_amdgcn_mfma_f32_32x32x16_f16(Al1, Bh[1], acc, 0, 0, 0);
        acc = __builtin_amdgcn_mfma_f32_32x32x16_f16(Ah1, Bl[1], acc, 0, 0, 0);
        acc = __builtin_amdgcn_mfma_f32_32x32x16_f16(Ah2, Bh[2], acc, 0, 0, 0);
        acc = __builtin_amdgcn_mfma_f32_32x32x16_f16(Al2, Bh[2], acc, 0, 0, 0);
        acc = __builtin_amdgcn_mfma_f32_32x32x16_f16(Ah2, Bl[2], acc, 0, 0, 0);
        acc = __builtin_amdgcn_mfma_f32_32x32x16_f16(Ah3, Bh[3], acc, 0, 0, 0);
        acc = __builtin_amdgcn_mfma_f32_32x32x16_f16(Al3, Bh[3], acc, 0, 0, 0);
        acc = __builtin_amdgcn_mfma_f32_32x32x16_f16(Ah3, Bl[3], acc, 0, 0, 0);

        // per-lane argmin update over this lane's 16 code rows
        // row(r) = (r&3) + 8*(r>>2) + hi4 + nt*32 — increasing in (nt, r):
        // strict '>' keeps first (lowest index) maximum => first-min of distance
        const int nbase = nt * 32 + hi4;
#pragma unroll
        for (int r = 0; r < 16; ++r) {
            float m = acc[r];
            int   n = nbase + ((r & 3) + 8 * (r >> 2));
            if (m > maxv) { maxv = m; maxn = n; }
        }

        // write prefetched chunk into the other buffer (forces vmcnt wait here,
        // after compute), then one barrier ends the iteration
        if (nt < 15) {
            *(float4*)((char*)&As[p ^ 1][0]    + tid * 16) = nh;
            *(float4*)((char*)&As[p ^ 1][2048] + tid * 16) = nl;
        }
        __syncthreads();
    }

    // ---- merge the two row-halves (lane <-> lane+32) ----
    {
        float ov = __shfl_xor(maxv, 32);
        int   on = __shfl_xor(maxn, 32);
        if (ov > maxv || (ov == maxv && on < maxn)) { maxv = ov; maxn = on; }
    }

    if (hi == 0) {
        Is[w * 32 + l31] = maxn;
        atomicAdd(&counts[c * MCODE + maxn], 1);
        outIdx[(size_t)(n0tk + w * 32 + l31) * NCB + c] = (float)maxn;
    }
    __syncthreads();

    // ---- quantized_st + loss (original fp32 emb + fp32 x for exactness) ----
    float lloss = 0.f;
#pragma unroll
    for (int i = 0; i < 8; ++i) {
        int q = tid + i * 256;
        int tok = q >> 4, d4 = q & 15;
        int idx = Is[tok];
        float mv = mask[(size_t)(n0tk + tok) * NCB + c];
        float4 e4 = *(const float4*)(emb + ((size_t)c * MCODE + idx) * DIM + d4 * 4);
        float4 x4 = *(const float4*)(x + (size_t)(n0tk + tok) * (NCB * DIM) + c * DIM + d4 * 4);
        float qx = e4.x * mv, qy = e4.y * mv, qz = e4.z * mv, qw = e4.w * mv;
        float4 o;
        o.x = x4.x + (qx - x4.x);
        o.y = x4.y + (qy - x4.y);
        o.z = x4.z + (qz - x4.z);
        o.w = x4.w + (qw - x4.w);
        *(float4*)(outQ + (size_t)(n0tk + tok) * (NCB * DIM) + c * DIM + d4 * 4) = o;
        float dx = x4.x - qx, dy = x4.y - qy, dz = x4.z - qz, dw = x4.w - qw;
        lloss += dx * dx + dy * dy + dz * dz + dw * dw;
    }
#pragma unroll
    for (int off = 32; off > 0; off >>= 1) lloss += __shfl_xor(lloss, off);
    if ((tid & 63) == 0) wls[tid >> 6] = lloss;
    __syncthreads();
    if (tid == 0) {
        float s = wls[0] + wls[1] + wls[2] + wls[3];
        atomicAdd(lossSum, s);
    }
}

__global__ __launch_bounds__(256) void finalize_kernel(const int* __restrict__ counts,
                                                       const float* __restrict__ lossSum,
                                                       float* __restrict__ out) {
    __shared__ float wls[4];
    int tid = threadIdx.x;
    float s = 0.f;
#pragma unroll
    for (int i = 0; i < 8; ++i) {
        int j = tid + i * 256;
        float p = (float)counts[j] * (1.0f / 65536.0f);
        s += p * logf(p + 1e-10f);
    }
#pragma unroll
    for (int off = 32; off > 0; off >>= 1) s += __shfl_xor(s, off);
    if ((tid & 63) == 0) wls[tid >> 6] = s;
    __syncthreads();
    if (tid == 0) {
        float tot = wls[0] + wls[1] + wls[2] + wls[3];
        float L = *lossSum * (1.0f / (float)QST_SIZE);
        out[QST_SIZE + 0] = 0.25f * L;   // commitment_loss
        out[QST_SIZE + 1] = L;           // codebook_loss
        out[QST_SIZE + 2] = expf(-tot);  // perplexity
    }
}

extern "C" void kernel_launch(void* const* d_in, const int* in_sizes, int n_in,
                              void* d_out, int out_size, void* d_ws, size_t ws_size,
                              hipStream_t stream) {
    const float* x    = (const float*)d_in[0];
    const float* emb  = (const float*)d_in[1];
    const float* mask = (const float*)d_in[2];
    float* out = (float*)d_out;

    _Float16* ehf  = (_Float16*)((char*)d_ws + WS_EH);
    _Float16* elf  = (_Float16*)((char*)d_ws + WS_EL);
    float* d0p     = (float*)((char*)d_ws + WS_D0);
    int*   counts  = (int*)((char*)d_ws + WS_CNT);
    float* lossSum = (float*)((char*)d_ws + WS_LOSS);

    prep_kernel<<<dim3(512), dim3(256), 0, stream>>>(emb, ehf, elf, d0p, counts, lossSum);
    vq_main<<<dim3(NTOK / TOK_TILE, NCB), dim3(256), 0, stream>>>(
        x, emb, mask, ehf, elf, d0p, counts, lossSum, out, out + IDX_OFF);
    finalize_kernel<<<dim3(1), dim3(256), 0, stream>>>(counts, lossSum, out);
}